// Round 13
// baseline (1701.979 us; speedup 1.0000x reference)
//
#include <hip/hip_runtime.h>
#include <cmath>

#define TT 256
#define BB 512
#define DD 128
#define HH 128
#define NCOL 528   // 4*H + 16 quantum-angle cols
#define KK 256
#define NCPAD 576  // 9 * 64

// ---------------- weight pack ----------------
// Wxp[528][128]                  : x-half row-major (xgemm staging)
// Whr4 float4[j][t] (j=g*4+k4)   : h-half main cols; thread t=h*8+ks owns cols
//                                  {g*128+h, g=0..3}, k-seg ks (16 k each)
// Whql[16][128]                  : h-half quantum cols (staged skewed to LDS in rec)
// bcat[576]
__global__ __launch_bounds__(256) void pack_weights(
    const float* __restrict__ Wf, const float* __restrict__ bf,
    const float* __restrict__ Wfq, const float* __restrict__ bfq,
    const float* __restrict__ Wi, const float* __restrict__ bi,
    const float* __restrict__ Wiq, const float* __restrict__ biq,
    const float* __restrict__ Wg, const float* __restrict__ bg,
    const float* __restrict__ Wgq, const float* __restrict__ bgq,
    const float* __restrict__ Wo, const float* __restrict__ bo,
    const float* __restrict__ Woq, const float* __restrict__ boq,
    float* __restrict__ Wxp, float* __restrict__ Whr4,
    float* __restrict__ Whql, float* __restrict__ bcat)
{
    int idx = blockIdx.x * blockDim.x + threadIdx.x;
    if (idx < NCOL * KK) {
        int c = idx >> 8, k = idx & 255;
        const float* srcW; int cl;
        if (c < 512) { int g = c >> 7; cl = c & 127;
            srcW = (g == 0) ? Wf : (g == 1) ? Wi : (g == 2) ? Wg : Wo; }
        else { int g = (c - 512) >> 2; cl = (c - 512) & 3;
            srcW = (g == 0) ? Wfq : (g == 1) ? Wiq : (g == 2) ? Wgq : Woq; }
        float v = srcW[(size_t)cl * KK + k];
        if (k < 128) Wxp[(size_t)c * 128 + k] = v;
        else {
            int kk = k - 128;
            if (c < 512) {
                int gate = c >> 7, hcol = c & 127;
                int t = hcol * 8 + (kk >> 4);          // 0..1023
                int j = gate * 4 + ((kk >> 2) & 3);    // 0..15
                Whr4[((size_t)j * 1024 + t) * 4 + (kk & 3)] = v;
            } else {
                Whql[(size_t)(c - 512) * 128 + kk] = v;
            }
        }
    }
    if (idx < NCPAD) {
        float b = 0.f;
        int c = idx;
        if (c < 512) { int g = c >> 7; int cl = c & 127;
            b = (g == 0) ? bf[cl] : (g == 1) ? bi[cl] : (g == 2) ? bg[cl] : bo[cl]; }
        else if (c < NCOL) { int g = (c - 512) >> 2; int cl = (c - 512) & 3;
            b = (g == 0) ? bfq[cl] : (g == 1) ? biq[cl] : (g == 2) ? bgq[cl] : boq[cl]; }
        bcat[c] = b;
    }
}

// ---------------- phase 1: Zx = X @ Wx^T + bcat  (M x 528, K=128) ----------------
#define P1_BM 128
#define P1_BN 64
#define ATP 132
#define BTP 68
__global__ __launch_bounds__(256, 3) void xgemm(
    const float* __restrict__ X, const float* __restrict__ Wxp,
    const float* __restrict__ bcat, float* __restrict__ Zx)
{
    __shared__ float At[64][ATP];
    __shared__ float Bt[64][BTP];
    const int tid = threadIdx.x;
    const int m0 = blockIdx.x * P1_BM;
    const int c0 = blockIdx.y * P1_BN;
    const int tm = tid >> 3;
    const int tn = tid & 7;
    float acc[4][8] = {};

    for (int khf = 0; khf < 2; ++khf) {
        #pragma unroll
        for (int j = 0; j < 8; ++j) {
            int fidx = tid + 256 * j;
            int m = fidx >> 4, k4 = (fidx & 15) * 4;
            float4 v = *(const float4*)(X + (size_t)(m0 + m) * 128 + khf * 64 + k4);
            At[k4 + 0][m] = v.x; At[k4 + 1][m] = v.y; At[k4 + 2][m] = v.z; At[k4 + 3][m] = v.w;
        }
        #pragma unroll
        for (int j = 0; j < 4; ++j) {
            int fidx = tid + 256 * j;
            int c = fidx >> 4, k4 = (fidx & 15) * 4;
            int cg = c0 + c;
            float4 v = make_float4(0.f, 0.f, 0.f, 0.f);
            if (cg < NCOL) v = *(const float4*)(Wxp + (size_t)cg * 128 + khf * 64 + k4);
            Bt[k4 + 0][c] = v.x; Bt[k4 + 1][c] = v.y; Bt[k4 + 2][c] = v.z; Bt[k4 + 3][c] = v.w;
        }
        __syncthreads();
        #pragma unroll 4
        for (int k = 0; k < 64; ++k) {
            float4 a  = *(const float4*)&At[k][tm * 4];
            float4 b0 = *(const float4*)&Bt[k][tn * 8];
            float4 b1 = *(const float4*)&Bt[k][tn * 8 + 4];
            float av[4] = {a.x, a.y, a.z, a.w};
            float bv[8] = {b0.x, b0.y, b0.z, b0.w, b1.x, b1.y, b1.z, b1.w};
            #pragma unroll
            for (int i = 0; i < 4; ++i)
                #pragma unroll
                for (int j = 0; j < 8; ++j)
                    acc[i][j] = fmaf(av[i], bv[j], acc[i][j]);
        }
        __syncthreads();
    }
    int c = c0 + tn * 8;
    if (c < NCOL) {
        float4 ba = *(const float4*)(bcat + c);
        float4 bb = *(const float4*)(bcat + c + 4);
        #pragma unroll
        for (int i = 0; i < 4; ++i) {
            int m = m0 + tm * 4 + i;
            float4 o0, o1;
            o0.x = acc[i][0] + ba.x; o0.y = acc[i][1] + ba.y;
            o0.z = acc[i][2] + ba.z; o0.w = acc[i][3] + ba.w;
            o1.x = acc[i][4] + bb.x; o1.y = acc[i][5] + bb.y;
            o1.z = acc[i][6] + bb.z; o1.w = acc[i][7] + bb.w;
            *(float4*)(Zx + (size_t)m * NCOL + c)     = o0;
            *(float4*)(Zx + (size_t)m * NCOL + c + 4) = o1;
        }
    }
}

// ---------------- phase 2: recurrence ----------------
__device__ __forceinline__ float sigm(float x) { return 1.0f / (1.0f + __expf(-x)); }
__device__ __forceinline__ float tanh_f(float x) {
    float e = __expf(2.f * x);
    return 1.f - 2.f / (e + 1.f);
}

// macro params must NOT be named x/y/z/w
#define FMA4(acc, Wv, Xv) acc = fmaf((Wv).x, (Xv).x, fmaf((Wv).y, (Xv).y, fmaf((Wv).z, (Xv).z, fmaf((Wv).w, (Xv).w, (acc)))))

// reduce over the 8 k-segment lanes: xor4 via ds_swizzle, xor2/xor1 via DPP quad_perm
#define XOR4RED(v) { \
    v += __int_as_float(__builtin_amdgcn_ds_swizzle(__float_as_int(v), 0x101F)); }
#define DPPRED(v) { \
    v += __int_as_float(__builtin_amdgcn_update_dpp(0, __float_as_int(v), 0xB1, 0xF, 0xF, true)); \
    v += __int_as_float(__builtin_amdgcn_update_dpp(0, __float_as_int(v), 0x4E, 0xF, 0xF, true)); }

// skewed h index: 8 k-segments (16 floats each) on disjoint bank quads, 16B-aligned bases
__device__ __forceinline__ int hsk(int k) { return k + 4 * (k >> 4); }  // max 155

// 1024 threads (16 waves, 4/SIMD). launch_bounds implies <=128 VGPR: weights (64)
// + working set (~50) genuinely fit in arch VGPRs.
__global__ __launch_bounds__(1024) void qlstm_rec(
    const float* __restrict__ Zx,      // [TC][512][528]
    const float* __restrict__ Whr4,    // float4 [16][1024]
    const float* __restrict__ Whql,    // [16][128]
    const float* __restrict__ hx0, const float* __restrict__ cx0,
    float* __restrict__ stateH, float* __restrict__ stateC,
    const float* __restrict__ Wq, const float* __restrict__ bq,
    const float* __restrict__ thf, const float* __restrict__ thi,
    const float* __restrict__ thg, const float* __restrict__ tho,
    float* __restrict__ out, int t0, int TC)
{
    __shared__ __align__(16) float hL[2][160];      // skewed
    __shared__ __align__(16) float WhqLs[16][160];  // q weights, same skew
    __shared__ __align__(16) float cEd[2][20];
    __shared__ __align__(16) float cEc[2][20];

    const int tid  = threadIdx.x;
    const int row0 = blockIdx.x * 2;
    const int ks   = tid & 7;        // k-segment (16 k each)
    const int h    = tid >> 3;       // 0..127

    // ---- main weights: 16 float4 = 64 VGPR, coalesced ----
    const float4* Wp4 = (const float4*)Whr4;
    float4 wv[16];
    #pragma unroll
    for (int j = 0; j < 16; ++j) wv[j] = Wp4[j * 1024 + tid];

    // ---- stage q-col weights to skewed LDS ----
    #pragma unroll
    for (int j = 0; j < 2; ++j) {
        int i = tid + 1024 * j;      // 0..2047
        WhqLs[i >> 7][hsk(i & 127)] = Whql[i];
    }

    // ---- per-thread invariants ----
    const bool isCell = (ks < 2);
    const int  r      = ks & 1;
    float4 wqv = make_float4(0.f, 0.f, 0.f, 0.f);
    float bb = 0.f, cxr = 0.f;
    if (isCell) {
        wqv = *(const float4*)(Wq + h * 4);
        bb  = bq[h];
    }
    // q-tasks: 32 tasks x 8 lanes on waves 0-3 (tid<256): task id = h
    const bool isQ = (tid < 256);
    const int rq  = h & 1;
    const int qc  = (h >> 1) & 15;
    const int qg  = qc >> 2, qw = qc & 3;
    float qcoef = 1.f, qth3 = 0.f;
    if (isQ) {
        const float* thp = (qg == 0) ? thf : (qg == 1) ? thi : (qg == 2) ? thg : tho;
        qcoef = (qw < 3) ? cosf(thp[qw]) : 1.f;
        qth3  = thp[3];
    }
    if (isCell) {
        const float* hs = (t0 == 0) ? hx0 : stateH;
        const float* cs = (t0 == 0) ? cx0 : stateC;
        hL[r][hsk(h)] = hs[(size_t)(row0 + r) * HH + h];
        cxr           = cs[(size_t)(row0 + r) * HH + h];
    }
    __syncthreads();

    // loop-invariant LDS pointers (16B-aligned bases)
    const float4* h0p = (const float4*)&hL[0][20 * ks];
    const float4* h1p = (const float4*)&hL[1][20 * ks];
    const float4* hqp = (const float4*)&hL[rq][20 * ks];
    const float4* qwp = (const float4*)&WhqLs[qc][20 * ks];

    // incremental global pointers
    const float* zbase = Zx + (size_t)row0 * NCOL;
    float*       outp  = out + (((size_t)t0 * BB) + row0 + r) * HH + h;

    for (int tc = 0; tc < TC; ++tc) {
        // prefetch (latency hidden under GEMM)
        float zc0 = 0, zc1 = 0, zc2 = 0, zc3 = 0, zqv = 0;
        if (isCell) {
            const float* zp = zbase + (size_t)r * NCOL + h;
            zc0 = zp[0]; zc1 = zp[128]; zc2 = zp[256]; zc3 = zp[384];
        }
        if (isQ) zqv = zbase[(size_t)rq * NCOL + 512 + qc];

        // ---- h-GEMM: 4 gate-cols (own h) x 16 k x 2 rows; q-dot rides along ----
        float aF0 = 0, aF1 = 0, aI0 = 0, aI1 = 0, aG0 = 0, aG1 = 0, aO0 = 0, aO1 = 0;
        float qa = 0.f;
        #pragma unroll
        for (int k4 = 0; k4 < 4; ++k4) {
            float4 hv0 = h0p[k4];
            float4 hv1 = h1p[k4];
            FMA4(aF0, wv[k4],      hv0);  FMA4(aF1, wv[k4],      hv1);
            FMA4(aI0, wv[4 + k4],  hv0);  FMA4(aI1, wv[4 + k4],  hv1);
            FMA4(aG0, wv[8 + k4],  hv0);  FMA4(aG1, wv[8 + k4],  hv1);
            FMA4(aO0, wv[12 + k4], hv0);  FMA4(aO1, wv[12 + k4], hv1);
        }
        if (isQ) {
            #pragma unroll
            for (int k4 = 0; k4 < 4; ++k4) {
                float4 wq4 = qwp[k4];
                float4 hq  = hqp[k4];
                FMA4(qa, wq4, hq);
            }
        }
        // allreduce over the 8 k-segment lanes
        XOR4RED(aF0) XOR4RED(aF1) XOR4RED(aI0) XOR4RED(aI1)
        XOR4RED(aG0) XOR4RED(aG1) XOR4RED(aO0) XOR4RED(aO1)
        XOR4RED(qa)
        DPPRED(aF0) DPPRED(aF1) DPPRED(aI0) DPPRED(aI1)
        DPPRED(aG0) DPPRED(aG1) DPPRED(aO0) DPPRED(aO1)
        DPPRED(qa)

        // ---- q-tasks: angle -> cosines published to LDS ----
        if (isQ) {
            float a = zqv + qa;
            float c = __cosf(a);
            float dval = (qw < 3) ? qcoef * c : __cosf(a + qth3);
            if (ks == 0) {
                cEd[rq][qc] = dval;
                cEc[rq][qc] = c;
            }
        }
        __syncthreads();   // cE* visible; all hL reads done

        // ---- fused cell update ----
        if (isCell) {
            float pf = zc0 + (r ? aF1 : aF0);
            float pi = zc1 + (r ? aI1 : aI0);
            float pg = zc2 + (r ? aG1 : aG0);
            float po = zc3 + (r ? aO1 : aO0);
            float qz[4];
            #pragma unroll
            for (int g = 0; g < 4; ++g) {
                float4 dv = *(const float4*)&cEd[r][g * 4];
                float4 cv = *(const float4*)&cEc[r][g * 4];
                float c01  = cv.x * cv.y;
                float c012 = c01 * cv.z;
                qz[g] = fmaf(dv.x, wqv.x,
                        fmaf(dv.y * cv.x, wqv.y,
                        fmaf(dv.z * c01, wqv.z,
                        fmaf(dv.w * c012, wqv.w, bb))));
            }
            float f  = sigm(pf)   + sigm(qz[0]);
            float ii = sigm(pi)   + sigm(qz[1]);
            float gg = tanh_f(pg) + tanh_f(qz[2]);
            float oo = sigm(po)   + sigm(qz[3]);
            float cn = fmaf(f, cxr, ii * gg);
            cxr = cn;
            float hn = oo * tanh_f(cn);
            hL[r][hsk(h)] = hn;
            *outp = hn;
        }
        __syncthreads();   // h_{t+1} visible
        zbase += (size_t)BB * NCOL;
        outp  += (size_t)BB * HH;
    }

    if (isCell) {
        float hn = hL[r][hsk(h)];
        stateH[(size_t)(row0 + r) * HH + h] = hn;
        stateC[(size_t)(row0 + r) * HH + h] = cxr;
        if (t0 + TC == TT) {
            size_t base = (size_t)TT * BB * HH;
            out[base + (size_t)(row0 + r) * HH + h]                   = hn;
            out[base + (size_t)BB * HH + (size_t)(row0 + r) * HH + h] = cxr;
        }
    }
}

extern "C" void kernel_launch(void* const* d_in, const int* in_sizes, int n_in,
                              void* d_out, int out_size, void* d_ws, size_t ws_size,
                              hipStream_t stream) {
    const float* X   = (const float*)d_in[0];
    const float* hx0 = (const float*)d_in[1];
    const float* cx0 = (const float*)d_in[2];
    const float* Wf  = (const float*)d_in[3];
    const float* bf  = (const float*)d_in[4];
    const float* Wfq = (const float*)d_in[5];
    const float* bfq = (const float*)d_in[6];
    const float* thf = (const float*)d_in[7];
    const float* Wi  = (const float*)d_in[8];
    const float* bi  = (const float*)d_in[9];
    const float* Wiq = (const float*)d_in[10];
    const float* biq = (const float*)d_in[11];
    const float* thi = (const float*)d_in[12];
    const float* Wg  = (const float*)d_in[13];
    const float* bg  = (const float*)d_in[14];
    const float* Wgq = (const float*)d_in[15];
    const float* bgq = (const float*)d_in[16];
    const float* thg = (const float*)d_in[17];
    const float* Wo  = (const float*)d_in[18];
    const float* bo  = (const float*)d_in[19];
    const float* Woq = (const float*)d_in[20];
    const float* boq = (const float*)d_in[21];
    const float* tho = (const float*)d_in[22];
    const float* Wq  = (const float*)d_in[23];
    const float* bq  = (const float*)d_in[24];

    float* ws = (float*)d_ws;
    float* Wxp    = ws;                         // 528*128 = 67584
    float* Whr4   = Wxp + 528 * 128;            // 16*1024*4 = 65536
    float* Whql   = Whr4 + 65536;               // 16*128 = 2048
    float* bcatp  = Whql + 2048;                // 576
    float* stateH = bcatp + NCPAD;              // 65536
    float* stateC = stateH + 512 * 128;         // 65536
    float* Zxb    = stateC + 512 * 128;

    size_t fixed_bytes = (size_t)(Zxb - ws) * sizeof(float);
    int TC = 256;
    while (TC > 4 && fixed_bytes + (size_t)TC * 512 * NCOL * 4 > ws_size) TC >>= 1;

    pack_weights<<<(NCOL * KK + 255) / 256, 256, 0, stream>>>(
        Wf, bf, Wfq, bfq, Wi, bi, Wiq, biq, Wg, bg, Wgq, bgq, Wo, bo, Woq, boq,
        Wxp, Whr4, Whql, bcatp);

    for (int t0 = 0; t0 < TT; t0 += TC) {
        xgemm<<<dim3(TC * 512 / P1_BM, NCPAD / P1_BN), 256, 0, stream>>>(
            X + (size_t)t0 * BB * DD, Wxp, bcatp, Zxb);
        qlstm_rec<<<256, 1024, 0, stream>>>(
            Zxb, Whr4, Whql, hx0, cx0, stateH, stateC, Wq, bq,
            thf, thi, thg, tho, (float*)d_out, t0, TC);
    }
}

// Round 14
// 1415.874 us; speedup vs baseline: 1.2021x; 1.2021x over previous
//
#include <hip/hip_runtime.h>
#include <cmath>

#define TT 256
#define BB 512
#define DD 128
#define HH 128
#define NCOL 528   // 4*H + 16 quantum-angle cols
#define KK 256
#define NCPAD 576  // 9 * 64

// ---------------- weight pack ----------------
// Wxp[528][128]                  : x-half row-major (xgemm staging)
// Whr4 float4[j][t] (j=g*4+k4)   : h-half main cols; thread t=h*8+ks owns cols
//                                  {g*128+h, g=0..3}, k-seg ks (16 k each)
// Whql[16][128]                  : h-half quantum cols (staged skewed to LDS in rec)
// bcat[576]
__global__ __launch_bounds__(256) void pack_weights(
    const float* __restrict__ Wf, const float* __restrict__ bf,
    const float* __restrict__ Wfq, const float* __restrict__ bfq,
    const float* __restrict__ Wi, const float* __restrict__ bi,
    const float* __restrict__ Wiq, const float* __restrict__ biq,
    const float* __restrict__ Wg, const float* __restrict__ bg,
    const float* __restrict__ Wgq, const float* __restrict__ bgq,
    const float* __restrict__ Wo, const float* __restrict__ bo,
    const float* __restrict__ Woq, const float* __restrict__ boq,
    float* __restrict__ Wxp, float* __restrict__ Whr4,
    float* __restrict__ Whql, float* __restrict__ bcat)
{
    int idx = blockIdx.x * blockDim.x + threadIdx.x;
    if (idx < NCOL * KK) {
        int c = idx >> 8, k = idx & 255;
        const float* srcW; int cl;
        if (c < 512) { int g = c >> 7; cl = c & 127;
            srcW = (g == 0) ? Wf : (g == 1) ? Wi : (g == 2) ? Wg : Wo; }
        else { int g = (c - 512) >> 2; cl = (c - 512) & 3;
            srcW = (g == 0) ? Wfq : (g == 1) ? Wiq : (g == 2) ? Wgq : Woq; }
        float v = srcW[(size_t)cl * KK + k];
        if (k < 128) Wxp[(size_t)c * 128 + k] = v;
        else {
            int kk = k - 128;
            if (c < 512) {
                int gate = c >> 7, hcol = c & 127;
                int t = hcol * 8 + (kk >> 4);          // 0..1023
                int j = gate * 4 + ((kk >> 2) & 3);    // 0..15
                Whr4[((size_t)j * 1024 + t) * 4 + (kk & 3)] = v;
            } else {
                Whql[(size_t)(c - 512) * 128 + kk] = v;
            }
        }
    }
    if (idx < NCPAD) {
        float b = 0.f;
        int c = idx;
        if (c < 512) { int g = c >> 7; int cl = c & 127;
            b = (g == 0) ? bf[cl] : (g == 1) ? bi[cl] : (g == 2) ? bg[cl] : bo[cl]; }
        else if (c < NCOL) { int g = (c - 512) >> 2; int cl = (c - 512) & 3;
            b = (g == 0) ? bfq[cl] : (g == 1) ? biq[cl] : (g == 2) ? bgq[cl] : boq[cl]; }
        bcat[c] = b;
    }
}

// ---------------- phase 1: Zx = X @ Wx^T + bcat  (M x 528, K=128) ----------------
#define P1_BM 128
#define P1_BN 64
#define ATP 132
#define BTP 68
__global__ __launch_bounds__(256, 3) void xgemm(
    const float* __restrict__ X, const float* __restrict__ Wxp,
    const float* __restrict__ bcat, float* __restrict__ Zx)
{
    __shared__ float At[64][ATP];
    __shared__ float Bt[64][BTP];
    const int tid = threadIdx.x;
    const int m0 = blockIdx.x * P1_BM;
    const int c0 = blockIdx.y * P1_BN;
    const int tm = tid >> 3;
    const int tn = tid & 7;
    float acc[4][8] = {};

    for (int khf = 0; khf < 2; ++khf) {
        #pragma unroll
        for (int j = 0; j < 8; ++j) {
            int fidx = tid + 256 * j;
            int m = fidx >> 4, k4 = (fidx & 15) * 4;
            float4 v = *(const float4*)(X + (size_t)(m0 + m) * 128 + khf * 64 + k4);
            At[k4 + 0][m] = v.x; At[k4 + 1][m] = v.y; At[k4 + 2][m] = v.z; At[k4 + 3][m] = v.w;
        }
        #pragma unroll
        for (int j = 0; j < 4; ++j) {
            int fidx = tid + 256 * j;
            int c = fidx >> 4, k4 = (fidx & 15) * 4;
            int cg = c0 + c;
            float4 v = make_float4(0.f, 0.f, 0.f, 0.f);
            if (cg < NCOL) v = *(const float4*)(Wxp + (size_t)cg * 128 + khf * 64 + k4);
            Bt[k4 + 0][c] = v.x; Bt[k4 + 1][c] = v.y; Bt[k4 + 2][c] = v.z; Bt[k4 + 3][c] = v.w;
        }
        __syncthreads();
        #pragma unroll 4
        for (int k = 0; k < 64; ++k) {
            float4 a  = *(const float4*)&At[k][tm * 4];
            float4 b0 = *(const float4*)&Bt[k][tn * 8];
            float4 b1 = *(const float4*)&Bt[k][tn * 8 + 4];
            float av[4] = {a.x, a.y, a.z, a.w};
            float bv[8] = {b0.x, b0.y, b0.z, b0.w, b1.x, b1.y, b1.z, b1.w};
            #pragma unroll
            for (int i = 0; i < 4; ++i)
                #pragma unroll
                for (int j = 0; j < 8; ++j)
                    acc[i][j] = fmaf(av[i], bv[j], acc[i][j]);
        }
        __syncthreads();
    }
    int c = c0 + tn * 8;
    if (c < NCOL) {
        float4 ba = *(const float4*)(bcat + c);
        float4 bb = *(const float4*)(bcat + c + 4);
        #pragma unroll
        for (int i = 0; i < 4; ++i) {
            int m = m0 + tm * 4 + i;
            float4 o0, o1;
            o0.x = acc[i][0] + ba.x; o0.y = acc[i][1] + ba.y;
            o0.z = acc[i][2] + ba.z; o0.w = acc[i][3] + ba.w;
            o1.x = acc[i][4] + bb.x; o1.y = acc[i][5] + bb.y;
            o1.z = acc[i][6] + bb.z; o1.w = acc[i][7] + bb.w;
            *(float4*)(Zx + (size_t)m * NCOL + c)     = o0;
            *(float4*)(Zx + (size_t)m * NCOL + c + 4) = o1;
        }
    }
}

// ---------------- phase 2: recurrence ----------------
__device__ __forceinline__ float sigm(float x) { return 1.0f / (1.0f + __expf(-x)); }
__device__ __forceinline__ float tanh_f(float x) {
    float e = __expf(2.f * x);
    return 1.f - 2.f / (e + 1.f);
}

// macro params must NOT be named x/y/z/w
#define FMA4(acc, Wv, Xv) acc = fmaf((Wv).x, (Xv).x, fmaf((Wv).y, (Xv).y, fmaf((Wv).z, (Xv).z, fmaf((Wv).w, (Xv).w, (acc)))))

// reduce over the 8 k-segment lanes: xor4 via ds_swizzle, xor2/xor1 via DPP quad_perm
#define XOR4RED(v) { \
    v += __int_as_float(__builtin_amdgcn_ds_swizzle(__float_as_int(v), 0x101F)); }
#define DPPRED(v) { \
    v += __int_as_float(__builtin_amdgcn_update_dpp(0, __float_as_int(v), 0xB1, 0xF, 0xF, true)); \
    v += __int_as_float(__builtin_amdgcn_update_dpp(0, __float_as_int(v), 0x4E, 0xF, 0xF, true)); }

// skewed h index: 8 k-segments (16 floats each) on disjoint bank quads, 16B-aligned bases
__device__ __forceinline__ int hsk(int k) { return k + 4 * (k >> 4); }  // max 155

// 1024 threads (16 waves, 4/SIMD). waves_per_eu(4,4): VGPR cap 512/4 = 128;
// demand ~110 (64 weights + ~45 working) fits -> no AGPR shunt, no spill.
// (R13 lacked this attribute: allocator targeted 8 waves/EU = 64 VGPR and spilled.)
__global__ __launch_bounds__(1024)
__attribute__((amdgpu_waves_per_eu(4, 4)))
void qlstm_rec(
    const float* __restrict__ Zx,      // [TC][512][528]
    const float* __restrict__ Whr4,    // float4 [16][1024]
    const float* __restrict__ Whql,    // [16][128]
    const float* __restrict__ hx0, const float* __restrict__ cx0,
    float* __restrict__ stateH, float* __restrict__ stateC,
    const float* __restrict__ Wq, const float* __restrict__ bq,
    const float* __restrict__ thf, const float* __restrict__ thi,
    const float* __restrict__ thg, const float* __restrict__ tho,
    float* __restrict__ out, int t0, int TC)
{
    __shared__ __align__(16) float hL[2][160];      // skewed
    __shared__ __align__(16) float WhqLs[16][160];  // q weights, same skew
    __shared__ __align__(16) float cEd[2][20];
    __shared__ __align__(16) float cEc[2][20];

    const int tid  = threadIdx.x;
    const int row0 = blockIdx.x * 2;
    const int ks   = tid & 7;        // k-segment (16 k each)
    const int h    = tid >> 3;       // 0..127

    // ---- main weights: 16 float4 = 64 VGPR, coalesced ----
    const float4* Wp4 = (const float4*)Whr4;
    float4 wv[16];
    #pragma unroll
    for (int j = 0; j < 16; ++j) wv[j] = Wp4[j * 1024 + tid];

    // ---- stage q-col weights to skewed LDS ----
    #pragma unroll
    for (int j = 0; j < 2; ++j) {
        int i = tid + 1024 * j;      // 0..2047
        WhqLs[i >> 7][hsk(i & 127)] = Whql[i];
    }

    // ---- per-thread invariants ----
    const bool isCell = (ks < 2);
    const int  r      = ks & 1;
    float4 wqv = make_float4(0.f, 0.f, 0.f, 0.f);
    float bb = 0.f, cxr = 0.f;
    if (isCell) {
        wqv = *(const float4*)(Wq + h * 4);
        bb  = bq[h];
    }
    // q-tasks: 32 tasks x 8 lanes on waves 0-3 (tid<256): task id = h
    const bool isQ = (tid < 256);
    const int rq  = h & 1;
    const int qc  = (h >> 1) & 15;
    const int qg  = qc >> 2, qw = qc & 3;
    float qcoef = 1.f, qth3 = 0.f;
    if (isQ) {
        const float* thp = (qg == 0) ? thf : (qg == 1) ? thi : (qg == 2) ? thg : tho;
        qcoef = (qw < 3) ? cosf(thp[qw]) : 1.f;
        qth3  = thp[3];
    }
    if (isCell) {
        const float* hs = (t0 == 0) ? hx0 : stateH;
        const float* cs = (t0 == 0) ? cx0 : stateC;
        hL[r][hsk(h)] = hs[(size_t)(row0 + r) * HH + h];
        cxr           = cs[(size_t)(row0 + r) * HH + h];
    }
    __syncthreads();

    // loop-invariant LDS pointers (16B-aligned bases)
    const float4* h0p = (const float4*)&hL[0][20 * ks];
    const float4* h1p = (const float4*)&hL[1][20 * ks];
    const float4* hqp = (const float4*)&hL[rq][20 * ks];
    const float4* qwp = (const float4*)&WhqLs[qc][20 * ks];

    // incremental global pointers
    const float* zbase = Zx + (size_t)row0 * NCOL;
    float*       outp  = out + (((size_t)t0 * BB) + row0 + r) * HH + h;

    for (int tc = 0; tc < TC; ++tc) {
        // prefetch (latency hidden under GEMM)
        float zc0 = 0, zc1 = 0, zc2 = 0, zc3 = 0, zqv = 0;
        if (isCell) {
            const float* zp = zbase + (size_t)r * NCOL + h;
            zc0 = zp[0]; zc1 = zp[128]; zc2 = zp[256]; zc3 = zp[384];
        }
        if (isQ) zqv = zbase[(size_t)rq * NCOL + 512 + qc];

        // ---- h-GEMM: 4 gate-cols (own h) x 16 k x 2 rows; q-dot rides along ----
        float aF0 = 0, aF1 = 0, aI0 = 0, aI1 = 0, aG0 = 0, aG1 = 0, aO0 = 0, aO1 = 0;
        float qa = 0.f;
        #pragma unroll
        for (int k4 = 0; k4 < 4; ++k4) {
            float4 hv0 = h0p[k4];
            float4 hv1 = h1p[k4];
            FMA4(aF0, wv[k4],      hv0);  FMA4(aF1, wv[k4],      hv1);
            FMA4(aI0, wv[4 + k4],  hv0);  FMA4(aI1, wv[4 + k4],  hv1);
            FMA4(aG0, wv[8 + k4],  hv0);  FMA4(aG1, wv[8 + k4],  hv1);
            FMA4(aO0, wv[12 + k4], hv0);  FMA4(aO1, wv[12 + k4], hv1);
        }
        if (isQ) {
            #pragma unroll
            for (int k4 = 0; k4 < 4; ++k4) {
                float4 wq4 = qwp[k4];
                float4 hq  = hqp[k4];
                FMA4(qa, wq4, hq);
            }
        }
        // allreduce over the 8 k-segment lanes
        XOR4RED(aF0) XOR4RED(aF1) XOR4RED(aI0) XOR4RED(aI1)
        XOR4RED(aG0) XOR4RED(aG1) XOR4RED(aO0) XOR4RED(aO1)
        XOR4RED(qa)
        DPPRED(aF0) DPPRED(aF1) DPPRED(aI0) DPPRED(aI1)
        DPPRED(aG0) DPPRED(aG1) DPPRED(aO0) DPPRED(aO1)
        DPPRED(qa)

        // ---- q-tasks: angle -> cosines published to LDS ----
        if (isQ) {
            float a = zqv + qa;
            float c = __cosf(a);
            float dval = (qw < 3) ? qcoef * c : __cosf(a + qth3);
            if (ks == 0) {
                cEd[rq][qc] = dval;
                cEc[rq][qc] = c;
            }
        }
        __syncthreads();   // cE* visible; all hL reads done

        // ---- fused cell update ----
        if (isCell) {
            float pf = zc0 + (r ? aF1 : aF0);
            float pi = zc1 + (r ? aI1 : aI0);
            float pg = zc2 + (r ? aG1 : aG0);
            float po = zc3 + (r ? aO1 : aO0);
            float qz[4];
            #pragma unroll
            for (int g = 0; g < 4; ++g) {
                float4 dv = *(const float4*)&cEd[r][g * 4];
                float4 cv = *(const float4*)&cEc[r][g * 4];
                float c01  = cv.x * cv.y;
                float c012 = c01 * cv.z;
                qz[g] = fmaf(dv.x, wqv.x,
                        fmaf(dv.y * cv.x, wqv.y,
                        fmaf(dv.z * c01, wqv.z,
                        fmaf(dv.w * c012, wqv.w, bb))));
            }
            float f  = sigm(pf)   + sigm(qz[0]);
            float ii = sigm(pi)   + sigm(qz[1]);
            float gg = tanh_f(pg) + tanh_f(qz[2]);
            float oo = sigm(po)   + sigm(qz[3]);
            float cn = fmaf(f, cxr, ii * gg);
            cxr = cn;
            float hn = oo * tanh_f(cn);
            hL[r][hsk(h)] = hn;
            *outp = hn;
        }
        __syncthreads();   // h_{t+1} visible
        zbase += (size_t)BB * NCOL;
        outp  += (size_t)BB * HH;
    }

    if (isCell) {
        float hn = hL[r][hsk(h)];
        stateH[(size_t)(row0 + r) * HH + h] = hn;
        stateC[(size_t)(row0 + r) * HH + h] = cxr;
        if (t0 + TC == TT) {
            size_t base = (size_t)TT * BB * HH;
            out[base + (size_t)(row0 + r) * HH + h]                   = hn;
            out[base + (size_t)BB * HH + (size_t)(row0 + r) * HH + h] = cxr;
        }
    }
}

extern "C" void kernel_launch(void* const* d_in, const int* in_sizes, int n_in,
                              void* d_out, int out_size, void* d_ws, size_t ws_size,
                              hipStream_t stream) {
    const float* X   = (const float*)d_in[0];
    const float* hx0 = (const float*)d_in[1];
    const float* cx0 = (const float*)d_in[2];
    const float* Wf  = (const float*)d_in[3];
    const float* bf  = (const float*)d_in[4];
    const float* Wfq = (const float*)d_in[5];
    const float* bfq = (const float*)d_in[6];
    const float* thf = (const float*)d_in[7];
    const float* Wi  = (const float*)d_in[8];
    const float* bi  = (const float*)d_in[9];
    const float* Wiq = (const float*)d_in[10];
    const float* biq = (const float*)d_in[11];
    const float* thi = (const float*)d_in[12];
    const float* Wg  = (const float*)d_in[13];
    const float* bg  = (const float*)d_in[14];
    const float* Wgq = (const float*)d_in[15];
    const float* bgq = (const float*)d_in[16];
    const float* thg = (const float*)d_in[17];
    const float* Wo  = (const float*)d_in[18];
    const float* bo  = (const float*)d_in[19];
    const float* Woq = (const float*)d_in[20];
    const float* boq = (const float*)d_in[21];
    const float* tho = (const float*)d_in[22];
    const float* Wq  = (const float*)d_in[23];
    const float* bq  = (const float*)d_in[24];

    float* ws = (float*)d_ws;
    float* Wxp    = ws;                         // 528*128 = 67584
    float* Whr4   = Wxp + 528 * 128;            // 16*1024*4 = 65536
    float* Whql   = Whr4 + 65536;               // 16*128 = 2048
    float* bcatp  = Whql + 2048;                // 576
    float* stateH = bcatp + NCPAD;              // 65536
    float* stateC = stateH + 512 * 128;         // 65536
    float* Zxb    = stateC + 512 * 128;

    size_t fixed_bytes = (size_t)(Zxb - ws) * sizeof(float);
    int TC = 256;
    while (TC > 4 && fixed_bytes + (size_t)TC * 512 * NCOL * 4 > ws_size) TC >>= 1;

    pack_weights<<<(NCOL * KK + 255) / 256, 256, 0, stream>>>(
        Wf, bf, Wfq, bfq, Wi, bi, Wiq, biq, Wg, bg, Wgq, bgq, Wo, bo, Woq, boq,
        Wxp, Whr4, Whql, bcatp);

    for (int t0 = 0; t0 < TT; t0 += TC) {
        xgemm<<<dim3(TC * 512 / P1_BM, NCPAD / P1_BN), 256, 0, stream>>>(
            X + (size_t)t0 * BB * DD, Wxp, bcatp, Zxb);
        qlstm_rec<<<256, 1024, 0, stream>>>(
            Zxb, Whr4, Whql, hx0, cx0, stateH, stateC, Wq, bq,
            thf, thi, thg, tho, (float*)d_out, t0, TC);
    }
}

// Round 16
// 1293.388 us; speedup vs baseline: 1.3159x; 1.0947x over previous
//
#include <hip/hip_runtime.h>
#include <cmath>

#define TT 256
#define BB 512
#define DD 128
#define HH 128
#define NCOL 528   // 4*H + 16 quantum-angle cols
#define KK 256
#define NCPAD 576
#define RWG 16          // rows per rec WG
#define NWGR (BB/RWG)   // 32
#define NTILE 33        // 32 main col-tiles + 1 q-tile

typedef __attribute__((ext_vector_type(8))) short short8v;
typedef __attribute__((ext_vector_type(4))) float f32x4;

__device__ __forceinline__ unsigned short f2bf(float x) {
    unsigned u = __float_as_uint(x);
    u += 0x7FFFu + ((u >> 16) & 1u);
    return (unsigned short)(u >> 16);
}
__device__ __forceinline__ float bf2f(unsigned short b) {
    return __uint_as_float(((unsigned)b) << 16);
}

// ---------------- weight pack ----------------
// Wxp[528][128] fp32 (xgemm), bcat[576], and Whb: bf16 hi/lo B-fragments for rec:
// Whb[((t*4+kf)*2+hl)*512 + l*8 + e] = term(hl) of Wh[c=t*16+(l&15)][k=kf*32+(l>>4)*8+e]
__global__ __launch_bounds__(256) void pack_weights(
    const float* __restrict__ Wf, const float* __restrict__ bf,
    const float* __restrict__ Wfq, const float* __restrict__ bfq,
    const float* __restrict__ Wi, const float* __restrict__ bi,
    const float* __restrict__ Wiq, const float* __restrict__ biq,
    const float* __restrict__ Wg, const float* __restrict__ bg,
    const float* __restrict__ Wgq, const float* __restrict__ bgq,
    const float* __restrict__ Wo, const float* __restrict__ bo,
    const float* __restrict__ Woq, const float* __restrict__ boq,
    float* __restrict__ Wxp, unsigned short* __restrict__ Whb,
    float* __restrict__ bcat)
{
    int idx = blockIdx.x * blockDim.x + threadIdx.x;
    auto wval = [&](int c, int k) -> float {
        const float* srcW; int cl;
        if (c < 512) { int g = c >> 7; cl = c & 127;
            srcW = (g == 0) ? Wf : (g == 1) ? Wi : (g == 2) ? Wg : Wo; }
        else { int g = (c - 512) >> 2; cl = (c - 512) & 3;
            srcW = (g == 0) ? Wfq : (g == 1) ? Wiq : (g == 2) ? Wgq : Woq; }
        return srcW[(size_t)cl * KK + k];
    };
    if (idx < NTILE * 4 * 2 * 512) {
        int e = idx & 7, l = (idx >> 3) & 63, hl = (idx >> 9) & 1;
        int kf = (idx >> 10) & 3, t = idx >> 12;
        int c = t * 16 + (l & 15);
        int k = kf * 32 + ((l >> 4) << 3) + e;
        float v = wval(c, 128 + k);
        unsigned short hi = f2bf(v);
        Whb[idx] = hl ? f2bf(v - bf2f(hi)) : hi;
    }
    if (idx < NCOL * 128) {
        int c = idx >> 7, k = idx & 127;
        Wxp[(size_t)c * 128 + k] = wval(c, k);
    }
    if (idx < NCPAD) {
        float b = 0.f; int c = idx;
        if (c < 512) { int g = c >> 7; int cl = c & 127;
            b = (g == 0) ? bf[cl] : (g == 1) ? bi[cl] : (g == 2) ? bg[cl] : bo[cl]; }
        else if (c < NCOL) { int g = (c - 512) >> 2; int cl = (c - 512) & 3;
            b = (g == 0) ? bfq[cl] : (g == 1) ? biq[cl] : (g == 2) ? bgq[cl] : boq[cl]; }
        bcat[c] = b;
    }
}

// ---------------- phase 1: Zx = X @ Wx^T + bcat (unchanged) ----------------
#define P1_BM 128
#define P1_BN 64
#define ATP 132
#define BTP 68
__global__ __launch_bounds__(256, 3) void xgemm(
    const float* __restrict__ X, const float* __restrict__ Wxp,
    const float* __restrict__ bcat, float* __restrict__ Zx)
{
    __shared__ float At[64][ATP];
    __shared__ float Bt[64][BTP];
    const int tid = threadIdx.x;
    const int m0 = blockIdx.x * P1_BM;
    const int c0 = blockIdx.y * P1_BN;
    const int tm = tid >> 3;
    const int tn = tid & 7;
    float acc[4][8] = {};

    for (int khf = 0; khf < 2; ++khf) {
        #pragma unroll
        for (int j = 0; j < 8; ++j) {
            int fidx = tid + 256 * j;
            int m = fidx >> 4, k4 = (fidx & 15) * 4;
            float4 v = *(const float4*)(X + (size_t)(m0 + m) * 128 + khf * 64 + k4);
            At[k4 + 0][m] = v.x; At[k4 + 1][m] = v.y; At[k4 + 2][m] = v.z; At[k4 + 3][m] = v.w;
        }
        #pragma unroll
        for (int j = 0; j < 4; ++j) {
            int fidx = tid + 256 * j;
            int c = fidx >> 4, k4 = (fidx & 15) * 4;
            int cg = c0 + c;
            float4 v = make_float4(0.f, 0.f, 0.f, 0.f);
            if (cg < NCOL) v = *(const float4*)(Wxp + (size_t)cg * 128 + khf * 64 + k4);
            Bt[k4 + 0][c] = v.x; Bt[k4 + 1][c] = v.y; Bt[k4 + 2][c] = v.z; Bt[k4 + 3][c] = v.w;
        }
        __syncthreads();
        #pragma unroll 4
        for (int k = 0; k < 64; ++k) {
            float4 a  = *(const float4*)&At[k][tm * 4];
            float4 b0 = *(const float4*)&Bt[k][tn * 8];
            float4 b1 = *(const float4*)&Bt[k][tn * 8 + 4];
            float av[4] = {a.x, a.y, a.z, a.w};
            float bv[8] = {b0.x, b0.y, b0.z, b0.w, b1.x, b1.y, b1.z, b1.w};
            #pragma unroll
            for (int i = 0; i < 4; ++i)
                #pragma unroll
                for (int j = 0; j < 8; ++j)
                    acc[i][j] = fmaf(av[i], bv[j], acc[i][j]);
        }
        __syncthreads();
    }
    int c = c0 + tn * 8;
    if (c < NCOL) {
        float4 ba = *(const float4*)(bcat + c);
        float4 bb = *(const float4*)(bcat + c + 4);
        #pragma unroll
        for (int i = 0; i < 4; ++i) {
            int m = m0 + tm * 4 + i;
            float4 o0, o1;
            o0.x = acc[i][0] + ba.x; o0.y = acc[i][1] + ba.y;
            o0.z = acc[i][2] + ba.z; o0.w = acc[i][3] + ba.w;
            o1.x = acc[i][4] + bb.x; o1.y = acc[i][5] + bb.y;
            o1.z = acc[i][6] + bb.z; o1.w = acc[i][7] + bb.w;
            *(float4*)(Zx + (size_t)m * NCOL + c)     = o0;
            *(float4*)(Zx + (size_t)m * NCOL + c + 4) = o1;
        }
    }
}

// ---------------- phase 2: recurrence via MFMA ----------------
__device__ __forceinline__ float sigm(float x) { return 1.0f / (1.0f + __expf(-x)); }
__device__ __forceinline__ float tanh_f(float x) {
    float e = __expf(2.f * x);
    return 1.f - 2.f / (e + 1.f);
}
// INJECTIVE S col skew (R15 bug: (c>>5)&3 wrapped -> cols 116-127 collided with 128-139)
__device__ __forceinline__ int scol(int c) { return c + 4 * (c >> 5); }   // max 591
__device__ __forceinline__ int wsk(int h)  { return h + ((h >> 5) & 3); } // h<128: injective

#define MFMA(a, b, c) __builtin_amdgcn_mfma_f32_16x16x32_bf16((a), (b), (c), 0, 0, 0)

// 32 WGs x 512 threads (8 waves, 2/SIMD, 256-VGPR cap). Each WG owns 16 batch rows.
__global__ __launch_bounds__(512)
__attribute__((amdgpu_waves_per_eu(2, 2)))
void qlstm_rec(
    const float* __restrict__ Zx,              // [TC][512][528]
    const unsigned short* __restrict__ Whb,    // bf16 hi/lo B-frags
    const float* __restrict__ hx0, const float* __restrict__ cx0,
    float* __restrict__ stateH, float* __restrict__ stateC,
    const float* __restrict__ Wq, const float* __restrict__ bq,
    const float* __restrict__ thf, const float* __restrict__ thi,
    const float* __restrict__ thg, const float* __restrict__ tho,
    float* __restrict__ out, int t0, int TC)
{
    __shared__ __align__(16) float S[16][600];          // injective skewed cols
    __shared__ __align__(16) unsigned short hHi[16][136];
    __shared__ __align__(16) unsigned short hLo[16][136];
    __shared__ __align__(16) float cEd[16][16];
    __shared__ __align__(16) float cEc[16][16];
    __shared__ float WqT[4][160];
    __shared__ float bqS[160];

    const int tid  = threadIdx.x;
    const int wid  = tid >> 6, lane = tid & 63;
    const int row0g = blockIdx.x * RWG;

    // ---- B-fragments into registers (hi/lo), 5 tile slots (slot 4 = q-tile 32) ----
    short8v Bhi[5][4], Blo[5][4];
    #pragma unroll
    for (int i = 0; i < 5; ++i) {
        int t = (i < 4) ? (wid * 4 + i) : 32;
        #pragma unroll
        for (int kf = 0; kf < 4; ++kf) {
            size_t base = (size_t)((t * 4 + kf) * 2) * 512 + (size_t)lane * 8;
            Bhi[i][kf] = *(const short8v*)(Whb + base);
            Blo[i][kf] = *(const short8v*)(Whb + base + 512);
        }
    }

    if (tid < 128) {
        int s = wsk(tid);
        WqT[0][s] = Wq[tid * 4 + 0]; WqT[1][s] = Wq[tid * 4 + 1];
        WqT[2][s] = Wq[tid * 4 + 2]; WqT[3][s] = Wq[tid * 4 + 3];
        bqS[s] = bq[tid];
    }

    // wave-7 q-task invariants
    const int qc = lane & 15, qg = qc >> 2, qw = qc & 3;
    float qcoef = 1.f, qth3 = 0.f;
    if (wid == 7) {
        const float* thp = (qg == 0) ? thf : (qg == 1) ? thi : (qg == 2) ? thg : tho;
        qcoef = (qw < 3) ? cosf(thp[qw]) : 1.f;
        qth3  = thp[3];
    }

    // cell ids: thread -> (row crow, 4 h's starting at hb)
    const int crow = tid >> 5;
    const int hb   = (tid & 31) * 4;

    float4 cx4, hlast;
    {
        const float* hs = (t0 == 0) ? hx0 : stateH;
        const float* cs = (t0 == 0) ? cx0 : stateC;
        float4 h4 = *(const float4*)(hs + (size_t)(row0g + crow) * HH + hb);
        cx4 = *(const float4*)(cs + (size_t)(row0g + crow) * HH + hb);
        hlast = h4;
        #pragma unroll
        for (int j = 0; j < 4; ++j) {
            float hv = (&h4.x)[j];
            unsigned short hi = f2bf(hv);
            hHi[crow][hb + j] = hi;
            hLo[crow][hb + j] = f2bf(hv - bf2f(hi));
        }
    }
    __syncthreads();

    const float* zstep = Zx + (size_t)row0g * NCOL;
    float* outp = out + ((size_t)t0 * BB + row0g + crow) * HH + hb;

    // initial Zx prefetch (step 0)
    float4 zc0 = *(const float4*)(zstep + (size_t)crow * NCOL + 0 * 128 + hb);
    float4 zc1 = *(const float4*)(zstep + (size_t)crow * NCOL + 1 * 128 + hb);
    float4 zc2 = *(const float4*)(zstep + (size_t)crow * NCOL + 2 * 128 + hb);
    float4 zc3 = *(const float4*)(zstep + (size_t)crow * NCOL + 3 * 128 + hb);
    float zq0 = 0, zq1 = 0, zq2 = 0, zq3 = 0;
    if (wid == 7) {
        int rb4 = (lane >> 4) * 4;
        zq0 = zstep[(size_t)(rb4 + 0) * NCOL + 512 + qc];
        zq1 = zstep[(size_t)(rb4 + 1) * NCOL + 512 + qc];
        zq2 = zstep[(size_t)(rb4 + 2) * NCOL + 512 + qc];
        zq3 = zstep[(size_t)(rb4 + 3) * NCOL + 512 + qc];
    }

    for (int tc = 0; tc < TC; ++tc) {
        const size_t noff = (tc + 1 < TC) ? (size_t)BB * NCOL : 0;

        // ---- MFMA phase: S_h = h @ Wh^T (3-term bf16 split) ----
        const int arow = lane & 15, kb = (lane >> 4) * 8;
        f32x4 C0 = {0,0,0,0}, C1 = {0,0,0,0}, C2 = {0,0,0,0}, C3 = {0,0,0,0}, C4 = {0,0,0,0};
        #pragma unroll
        for (int kf = 0; kf < 4; ++kf) {
            short8v Ahi = *(const short8v*)&hHi[arow][kf * 32 + kb];
            short8v Alo = *(const short8v*)&hLo[arow][kf * 32 + kb];
            C0 = MFMA(Ahi, Bhi[0][kf], C0); C0 = MFMA(Alo, Bhi[0][kf], C0); C0 = MFMA(Ahi, Blo[0][kf], C0);
            C1 = MFMA(Ahi, Bhi[1][kf], C1); C1 = MFMA(Alo, Bhi[1][kf], C1); C1 = MFMA(Ahi, Blo[1][kf], C1);
            C2 = MFMA(Ahi, Bhi[2][kf], C2); C2 = MFMA(Alo, Bhi[2][kf], C2); C2 = MFMA(Ahi, Blo[2][kf], C2);
            C3 = MFMA(Ahi, Bhi[3][kf], C3); C3 = MFMA(Alo, Bhi[3][kf], C3); C3 = MFMA(Ahi, Blo[3][kf], C3);
            if (wid == 7) {
                C4 = MFMA(Ahi, Bhi[4][kf], C4); C4 = MFMA(Alo, Bhi[4][kf], C4); C4 = MFMA(Ahi, Blo[4][kf], C4);
            }
        }
        // S writes (C/D layout: col=lane&15, row=(lane>>4)*4+j)
        {
            const int cl = lane & 15, rb = (lane >> 4) * 4;
            #define SWRITE(Ci, ii) { int col = (wid * 4 + (ii)) * 16 + cl; int sc = scol(col); \
                S[rb + 0][sc] = (Ci)[0]; S[rb + 1][sc] = (Ci)[1]; \
                S[rb + 2][sc] = (Ci)[2]; S[rb + 3][sc] = (Ci)[3]; }
            SWRITE(C0, 0) SWRITE(C1, 1) SWRITE(C2, 2) SWRITE(C3, 3)
            #undef SWRITE
        }
        // wave 7: q-tile -> angles -> closed-form cosines, publish + reload zq
        if (wid == 7) {
            int rb4 = (lane >> 4) * 4;
            float a0 = C4[0] + zq0, a1 = C4[1] + zq1, a2 = C4[2] + zq2, a3 = C4[3] + zq3;
            float c0_ = __cosf(a0), c1_ = __cosf(a1), c2_ = __cosf(a2), c3_ = __cosf(a3);
            float d0 = (qw < 3) ? qcoef * c0_ : __cosf(a0 + qth3);
            float d1 = (qw < 3) ? qcoef * c1_ : __cosf(a1 + qth3);
            float d2 = (qw < 3) ? qcoef * c2_ : __cosf(a2 + qth3);
            float d3 = (qw < 3) ? qcoef * c3_ : __cosf(a3 + qth3);
            cEd[rb4 + 0][qc] = d0; cEc[rb4 + 0][qc] = c0_;
            cEd[rb4 + 1][qc] = d1; cEc[rb4 + 1][qc] = c1_;
            cEd[rb4 + 2][qc] = d2; cEc[rb4 + 2][qc] = c2_;
            cEd[rb4 + 3][qc] = d3; cEc[rb4 + 3][qc] = c3_;
            zq0 = zstep[noff + (size_t)(rb4 + 0) * NCOL + 512 + qc];
            zq1 = zstep[noff + (size_t)(rb4 + 1) * NCOL + 512 + qc];
            zq2 = zstep[noff + (size_t)(rb4 + 2) * NCOL + 512 + qc];
            zq3 = zstep[noff + (size_t)(rb4 + 3) * NCOL + 512 + qc];
        }
        __syncthreads();

        // ---- cell phase: 4 cells per thread ----
        {
            float4 sv0 = *(const float4*)&S[crow][scol(0 * 128 + hb)];
            float4 sv1 = *(const float4*)&S[crow][scol(1 * 128 + hb)];
            float4 sv2 = *(const float4*)&S[crow][scol(2 * 128 + hb)];
            float4 sv3 = *(const float4*)&S[crow][scol(3 * 128 + hb)];
            float4 pre0, pre1, pre2, pre3;
            pre0.x = zc0.x + sv0.x; pre0.y = zc0.y + sv0.y; pre0.z = zc0.z + sv0.z; pre0.w = zc0.w + sv0.w;
            pre1.x = zc1.x + sv1.x; pre1.y = zc1.y + sv1.y; pre1.z = zc1.z + sv1.z; pre1.w = zc1.w + sv1.w;
            pre2.x = zc2.x + sv2.x; pre2.y = zc2.y + sv2.y; pre2.z = zc2.z + sv2.z; pre2.w = zc2.w + sv2.w;
            pre3.x = zc3.x + sv3.x; pre3.y = zc3.y + sv3.y; pre3.z = zc3.z + sv3.z; pre3.w = zc3.w + sv3.w;
            // reload Zx for next step (covers next MFMA phase)
            zc0 = *(const float4*)(zstep + noff + (size_t)crow * NCOL + 0 * 128 + hb);
            zc1 = *(const float4*)(zstep + noff + (size_t)crow * NCOL + 1 * 128 + hb);
            zc2 = *(const float4*)(zstep + noff + (size_t)crow * NCOL + 2 * 128 + hb);
            zc3 = *(const float4*)(zstep + noff + (size_t)crow * NCOL + 3 * 128 + hb);
            // E factors per gate (shared by this thread's 4 cells)
            float E[4][4];
            #pragma unroll
            for (int g = 0; g < 4; ++g) {
                float4 dv = *(const float4*)&cEd[crow][g * 4];
                float4 cv = *(const float4*)&cEc[crow][g * 4];
                float c01 = cv.x * cv.y;
                E[g][0] = dv.x;
                E[g][1] = dv.y * cv.x;
                E[g][2] = dv.z * c01;
                E[g][3] = dv.w * (c01 * cv.z);
            }
            float4 hres;
            #pragma unroll
            for (int j = 0; j < 4; ++j) {
                int s = wsk(hb + j);
                float wq0 = WqT[0][s], wq1 = WqT[1][s], wq2 = WqT[2][s], wq3 = WqT[3][s];
                float bb = bqS[s];
                float qzf = fmaf(E[0][0], wq0, fmaf(E[0][1], wq1, fmaf(E[0][2], wq2, fmaf(E[0][3], wq3, bb))));
                float qzi = fmaf(E[1][0], wq0, fmaf(E[1][1], wq1, fmaf(E[1][2], wq2, fmaf(E[1][3], wq3, bb))));
                float qzg = fmaf(E[2][0], wq0, fmaf(E[2][1], wq1, fmaf(E[2][2], wq2, fmaf(E[2][3], wq3, bb))));
                float qzo = fmaf(E[3][0], wq0, fmaf(E[3][1], wq1, fmaf(E[3][2], wq2, fmaf(E[3][3], wq3, bb))));
                float f  = sigm((&pre0.x)[j])   + sigm(qzf);
                float ii = sigm((&pre1.x)[j])   + sigm(qzi);
                float gg = tanh_f((&pre2.x)[j]) + tanh_f(qzg);
                float oo = sigm((&pre3.x)[j])   + sigm(qzo);
                float cn = fmaf(f, (&cx4.x)[j], ii * gg);
                (&cx4.x)[j] = cn;
                float hn = oo * tanh_f(cn);
                (&hres.x)[j] = hn;
                unsigned short hi = f2bf(hn);
                hHi[crow][hb + j] = hi;
                hLo[crow][hb + j] = f2bf(hn - bf2f(hi));
            }
            *(float4*)outp = hres;
            hlast = hres;
        }
        __syncthreads();
        zstep += (size_t)BB * NCOL;
        outp  += (size_t)BB * HH;
    }

    // final state
    {
        size_t off = (size_t)(row0g + crow) * HH + hb;
        *(float4*)(stateH + off) = hlast;
        *(float4*)(stateC + off) = cx4;
        if (t0 + TC == TT) {
            size_t base = (size_t)TT * BB * HH;
            *(float4*)(out + base + off) = hlast;
            *(float4*)(out + base + (size_t)BB * HH + off) = cx4;
        }
    }
}

extern "C" void kernel_launch(void* const* d_in, const int* in_sizes, int n_in,
                              void* d_out, int out_size, void* d_ws, size_t ws_size,
                              hipStream_t stream) {
    const float* X   = (const float*)d_in[0];
    const float* hx0 = (const float*)d_in[1];
    const float* cx0 = (const float*)d_in[2];
    const float* Wf  = (const float*)d_in[3];
    const float* bf  = (const float*)d_in[4];
    const float* Wfq = (const float*)d_in[5];
    const float* bfq = (const float*)d_in[6];
    const float* thf = (const float*)d_in[7];
    const float* Wi  = (const float*)d_in[8];
    const float* bi  = (const float*)d_in[9];
    const float* Wiq = (const float*)d_in[10];
    const float* biq = (const float*)d_in[11];
    const float* thi = (const float*)d_in[12];
    const float* Wg  = (const float*)d_in[13];
    const float* bg  = (const float*)d_in[14];
    const float* Wgq = (const float*)d_in[15];
    const float* bgq = (const float*)d_in[16];
    const float* thg = (const float*)d_in[17];
    const float* Wo  = (const float*)d_in[18];
    const float* bo  = (const float*)d_in[19];
    const float* Woq = (const float*)d_in[20];
    const float* boq = (const float*)d_in[21];
    const float* tho = (const float*)d_in[22];
    const float* Wq  = (const float*)d_in[23];
    const float* bq  = (const float*)d_in[24];

    float* ws = (float*)d_ws;
    float* Wxp    = ws;                             // 67584 floats
    float* bcatp  = Wxp + 67584;                    // 576
    float* stateH = bcatp + 576;                    // 65536
    float* stateC = stateH + 65536;                 // 65536
    unsigned short* Whb = (unsigned short*)(stateC + 65536);  // 135168 ushort = 67584 float-slots
    float* Zxb    = stateC + 65536 + 67584;

    size_t fixed_bytes = (size_t)(Zxb - ws) * sizeof(float);
    int TC = 256;
    while (TC > 4 && fixed_bytes + (size_t)TC * 512 * NCOL * 4 > ws_size) TC >>= 1;

    int packN = NTILE * 4 * 2 * 512;   // 135168
    pack_weights<<<(packN + 255) / 256, 256, 0, stream>>>(
        Wf, bf, Wfq, bfq, Wi, bi, Wiq, biq, Wg, bg, Wgq, bgq, Wo, bo, Woq, boq,
        Wxp, Whb, bcatp);

    for (int t0 = 0; t0 < TT; t0 += TC) {
        xgemm<<<dim3(TC * 512 / P1_BM, NCPAD / P1_BN), 256, 0, stream>>>(
            X + (size_t)t0 * BB * DD, Wxp, bcatp, Zxb);
        qlstm_rec<<<NWGR, 512, 0, stream>>>(
            Zxb, Whb, hx0, cx0, stateH, stateC, Wq, bq,
            thf, thi, thg, tho, (float*)d_out, t0, TC);
    }
}